// Round 4
// baseline (467.447 us; speedup 1.0000x reference)
//
#include <hip/hip_runtime.h>

// rnn_lyapunov: B=64,T=2048,NIN=64,NH=512,NOUT=64
// Time-parallel chunked RNN, W=6 warmup (contraction ||A||<=0.36).
// R4: 32x32x16 MFMA, 8 main waves x (2mt x 2nt) -> minimal LDS(h) + L2(A)
// traffic; 8 helper waves do head + u staging concurrently; bias folded into
// an extra K-column (h row 512 == 1.0).

#define T_LEN 2048
#define H_DIM 512
#define N_IN  64
#define N_OUT 64
#define L_CH  8
#define W_UP  6
#define S_TOT (W_UP + 9)         // 15 iterations: head at s in [W+1, W+8]
#define ST_H  552                // shorts; 16B-aligned rows, bank-stride 20 (balanced)
#define ST_U  72

typedef __attribute__((ext_vector_type(8)))  short short8;   // 8 bf16
typedef __attribute__((ext_vector_type(4)))  float f32x4;
typedef __attribute__((ext_vector_type(16))) float f32x16;

__device__ __forceinline__ unsigned short f2bf(float f) {
  union { float f; unsigned u; } v; v.f = f;
  return (unsigned short)((v.u + 0x7FFFu + ((v.u >> 16) & 1u)) >> 16);  // RNE
}
__device__ __forceinline__ unsigned pack2bf(float a, float b) {
  return (unsigned)f2bf(a) | ((unsigned)f2bf(b) << 16);
}
__device__ __forceinline__ float tanh_fast(float x) {
  float e = __expf(2.f * x);
  float r = __builtin_amdgcn_rcpf(e + 1.f);
  return __builtin_fmaf(-2.f, r, 1.f);
}

#define MFMA32(a, b, c) __builtin_amdgcn_mfma_f32_32x32x16_bf16(a, b, c, 0, 0, 0)
#define MFMA16(a, b, c) __builtin_amdgcn_mfma_f32_16x16x32_bf16(a, b, c, 0, 0, 0)

// ---- pack ------------------------------------------------------------------
// 32x32x16 A-op: lane holds A[m = 32*mt + (L&31)][k = 16*kk + 8*(L>>5) + j]
// Apk  [kk=33][mt=16][lane][8] : kk<32 -> W_hh[m][k]*om[k]^2 ; kk=32 -> bias col
// WihPk[kk= 4][mt=16][lane][8] : W_ih[m][k]
// 16x16x32 A-op: lane holds A[m = 16*ot + (L&15)][k = 32*kk + 8*(L>>4) + j]
// WlinPk[kk=17][ot=4][lane][8] : kk<16 -> W_lin[m][k] ; kk=16 -> b_lin col
__global__ __launch_bounds__(256) void pack_kernel(
    const float* __restrict__ W_ih, const float* __restrict__ W_hh,
    const float* __restrict__ b_ih, const float* __restrict__ b_hh,
    const float* __restrict__ omega, const float* __restrict__ W_lin,
    const float* __restrict__ b_lin,
    unsigned short* __restrict__ Apk, unsigned short* __restrict__ WihPk,
    unsigned short* __restrict__ WlinPk)
{
  const int id = blockIdx.x * 256 + threadIdx.x;
  if (id < 33792) {                        // ---- Apk
    const int kk = id >> 10, mt = (id >> 6) & 15, lane = id & 63;
    const int r = lane & 31, h5 = lane >> 5;
    const int m = mt * 32 + r;
    unsigned short* dst = Apk + (size_t)id * 8;
    if (kk < 32) {
      const int k0 = kk * 16 + h5 * 8;
      #pragma unroll
      for (int j = 0; j < 8; j++) {
        const float om = omega[k0 + j];
        dst[j] = f2bf(W_hh[(size_t)m * H_DIM + k0 + j] * om * om);
      }
    } else {
      #pragma unroll
      for (int j = 0; j < 8; j++) {
        const int kp = h5 * 8 + j;
        dst[j] = (kp == 0) ? f2bf(b_ih[m] + b_hh[m]) : 0;
      }
    }
  } else if (id < 37888) {                 // ---- WihPk
    const int id2 = id - 33792;
    const int kk = id2 >> 10, mt = (id2 >> 6) & 15, lane = id2 & 63;
    const int r = lane & 31, h5 = lane >> 5;
    const int m = mt * 32 + r, k0 = kk * 16 + h5 * 8;
    unsigned short* dst = WihPk + (size_t)id2 * 8;
    #pragma unroll
    for (int j = 0; j < 8; j++) dst[j] = f2bf(W_ih[(size_t)m * N_IN + k0 + j]);
  } else if (id < 42240) {                 // ---- WlinPk
    const int id3 = id - 37888;
    const int kk = id3 >> 8, ot = (id3 >> 6) & 3, lane = id3 & 63;
    const int c = lane & 15, q = lane >> 4;
    const int m = ot * 16 + c;
    unsigned short* dst = WlinPk + (size_t)id3 * 8;
    if (kk < 16) {
      const int k0 = kk * 32 + q * 8;
      #pragma unroll
      for (int j = 0; j < 8; j++) dst[j] = f2bf(W_lin[(size_t)m * H_DIM + k0 + j]);
    } else {
      #pragma unroll
      for (int j = 0; j < 8; j++) dst[j] = (q * 8 + j == 0) ? f2bf(b_lin[m]) : 0;
    }
  }
}

// ---- main time-parallel recurrence -----------------------------------------
// 256 blocks x 1024 threads (16 waves, 1 block/CU). Waves 0-7: main GEMM,
// waves 8-11: head, waves 12-15: u staging.
__global__ __launch_bounds__(1024, 4) void rnn_kernel(
    const float* __restrict__ u,
    const unsigned short* __restrict__ Apk,
    const unsigned short* __restrict__ WihPk,
    const unsigned short* __restrict__ WlinPk,
    float* __restrict__ out)
{
  __shared__ __align__(16) unsigned short h_buf[2][64][ST_H];  // 141,312 B
  __shared__ __align__(16) unsigned short u_buf[2][64][ST_U];  //  18,432 B

  const int tid = threadIdx.x;
  const int w = tid >> 6, lane = tid & 63;
  const int rcol = lane & 31, h5 = lane >> 5;       // 32x32 indexing
  const int c = lane & 15, q = lane >> 4;           // 16x16 indexing (head)
  const int t0 = blockIdx.x * L_CH;

  // init: zero both h buffers (incl. ext cols), stage u for iteration 0
  for (int i = tid; i < 2 * 64 * ST_H / 2; i += 1024) ((unsigned*)h_buf)[i] = 0;
  {
    int t = t0 - W_UP; if (t < 0) t = 0;
    const int row = tid >> 4, cb = (tid & 15) * 4;
    const float* src = u + ((size_t)row * T_LEN + t) * N_IN + cb;
    unsigned* d = (unsigned*)&u_buf[0][row][cb];
    d[0] = pack2bf(src[0], src[1]); d[1] = pack2bf(src[2], src[3]);
  }
  __syncthreads();
  if (tid < 128) h_buf[tid >> 6][tid & 63][H_DIM] = 0x3F80;  // bf16 1.0 (bias row)
  __syncthreads();

  for (int s = 0; s < S_TOT; s++) {
    const int cur = s & 1, nxt = cur ^ 1;

    if (w < 8) {
      if (s < S_TOT - 1) {
        f32x16 acc[2][2];
        #pragma unroll
        for (int i = 0; i < 2; i++)
          #pragma unroll
          for (int j = 0; j < 2; j++)
            acc[i][j] = (f32x16)(0.f);

        // ---- A(L2) x h(LDS): K = 528 (incl. bias col) ----
        const unsigned short* ap = Apk + ((size_t)(2 * w) * 64 + lane) * 8;
        #pragma unroll 4
        for (int kk = 0; kk < 33; kk++) {
          const short8 hf0 = *(const short8*)&h_buf[cur][rcol][kk * 16 + h5 * 8];
          const short8 hf1 = *(const short8*)&h_buf[cur][32 + rcol][kk * 16 + h5 * 8];
          const short8 a0 = *(const short8*)(ap + (size_t)kk * 8192);
          const short8 a1 = *(const short8*)(ap + (size_t)kk * 8192 + 512);
          acc[0][0] = MFMA32(a0, hf0, acc[0][0]);
          acc[1][0] = MFMA32(a1, hf0, acc[1][0]);
          acc[0][1] = MFMA32(a0, hf1, acc[0][1]);
          acc[1][1] = MFMA32(a1, hf1, acc[1][1]);
        }
        // ---- + W_ih(L2) x u(LDS): K = 64 ----
        const unsigned short* wp = WihPk + ((size_t)(2 * w) * 64 + lane) * 8;
        #pragma unroll
        for (int kk = 0; kk < 4; kk++) {
          const short8 uf0 = *(const short8*)&u_buf[cur][rcol][kk * 16 + h5 * 8];
          const short8 uf1 = *(const short8*)&u_buf[cur][32 + rcol][kk * 16 + h5 * 8];
          const short8 a0 = *(const short8*)(wp + (size_t)kk * 8192);
          const short8 a1 = *(const short8*)(wp + (size_t)kk * 8192 + 512);
          acc[0][0] = MFMA32(a0, uf0, acc[0][0]);
          acc[1][0] = MFMA32(a1, uf0, acc[1][0]);
          acc[0][1] = MFMA32(a0, uf1, acc[0][1]);
          acc[1][1] = MFMA32(a1, uf1, acc[1][1]);
        }

        // ---- epilogue: h_new = tanh(acc) -> h_buf[nxt]
        // 32x32 D: col = lane&31 (batch), row = 8*(reg>>2) + 4*(lane>>5) + (reg&3)
        #pragma unroll
        for (int mtl = 0; mtl < 2; mtl++) {
          #pragma unroll
          for (int ntl = 0; ntl < 2; ntl++) {
            const f32x16 v = acc[mtl][ntl];
            unsigned short* rowp =
                &h_buf[nxt][ntl * 32 + rcol][(2 * w + mtl) * 32 + 4 * h5];
            #pragma unroll
            for (int jq = 0; jq < 4; jq++) {
              unsigned* d = (unsigned*)(rowp + 8 * jq);
              d[0] = pack2bf(tanh_fast(v[4 * jq]),     tanh_fast(v[4 * jq + 1]));
              d[1] = pack2bf(tanh_fast(v[4 * jq + 2]), tanh_fast(v[4 * jq + 3]));
            }
          }
        }
      }
    } else if (w < 12) {
      // ---- head (waves 8-11): out_t = W_lin_ext x h^{(s)} (reads h_buf[cur]) ----
      if (s >= W_UP + 1) {
        const int t = t0 + s - W_UP - 1;
        const int ot = w - 8;
        f32x4 hacc[4];
        #pragma unroll
        for (int bt = 0; bt < 4; bt++) hacc[bt] = (f32x4){0.f, 0.f, 0.f, 0.f};
        const unsigned short* lp = WlinPk + ((size_t)ot * 64 + lane) * 8;
        #pragma unroll 4
        for (int kk = 0; kk < 17; kk++) {
          const short8 a = *(const short8*)(lp + (size_t)kk * 2048);
          #pragma unroll
          for (int bt = 0; bt < 4; bt++) {
            const short8 hf = *(const short8*)&h_buf[cur][bt * 16 + c][kk * 32 + q * 8];
            hacc[bt] = MFMA16(a, hf, hacc[bt]);
          }
        }
        #pragma unroll
        for (int bt = 0; bt < 4; bt++) {
          float* op = out + ((size_t)(bt * 16 + c) * T_LEN + t) * N_OUT + ot * 16 + q * 4;
          *(f32x4*)op = hacc[bt];
        }
      }
    } else {
      // ---- u staging (waves 12-15): u_{tau(s+1)} -> u_buf[nxt] ----
      if (s < S_TOT - 2) {
        int tn = t0 - W_UP + s + 1;
        tn = tn < 0 ? 0 : (tn > T_LEN - 1 ? T_LEN - 1 : tn);
        const int ht = (w - 12) * 64 + lane;          // 0..255
        const int row = ht >> 2, cb = (ht & 3) * 16;  // 16 floats/thread
        const float* src = u + ((size_t)row * T_LEN + tn) * N_IN + cb;
        unsigned* d = (unsigned*)&u_buf[nxt][row][cb];
        #pragma unroll
        for (int p = 0; p < 8; p++) d[p] = pack2bf(src[2 * p], src[2 * p + 1]);
      }
    }
    __syncthreads();
  }
}

extern "C" void kernel_launch(void* const* d_in, const int* in_sizes, int n_in,
                              void* d_out, int out_size, void* d_ws, size_t ws_size,
                              hipStream_t stream) {
  const float* u     = (const float*)d_in[0];
  const float* W_ih  = (const float*)d_in[1];
  const float* W_hh  = (const float*)d_in[2];
  const float* b_ih  = (const float*)d_in[3];
  const float* b_hh  = (const float*)d_in[4];
  const float* omega = (const float*)d_in[5];
  const float* W_lin = (const float*)d_in[6];
  const float* b_lin = (const float*)d_in[7];
  float* out = (float*)d_out;

  unsigned short* Apk    = (unsigned short*)d_ws;       // 33*16*64*8 = 270,336 sh
  unsigned short* WihPk  = Apk + (size_t)33 * 16 * 64 * 8;   // 4*16*64*8
  unsigned short* WlinPk = WihPk + (size_t)4 * 16 * 64 * 8;  // 17*4*64*8

  pack_kernel<<<165, 256, 0, stream>>>(W_ih, W_hh, b_ih, b_hh, omega, W_lin,
                                       b_lin, Apk, WihPk, WlinPk);
  rnn_kernel<<<T_LEN / L_CH, 1024, 0, stream>>>(u, Apk, WihPk, WlinPk, out);
}

// Round 5
// 405.451 us; speedup vs baseline: 1.1529x; 1.1529x over previous
//
#include <hip/hip_runtime.h>

// rnn_lyapunov: B=64,T=2048,NIN=64,NH=512,NOUT=64
// Time-parallel chunked RNN, W=6 warmup (contraction ||A||<=0.36).
// R5: R4 structure (32x32x16 MFMA, 8 main waves x 2mt x 2nt = minimal LDS+L2
// traffic, bias folded as K-column) but 768 threads / 12 waves:
// __launch_bounds__(768,3) -> 170-reg cap, kills the R4 scratch spill that
// caused 530MB HBM fetch. Waves 8-11 run head then u-staging concurrently.

#define T_LEN 2048
#define H_DIM 512
#define N_IN  64
#define N_OUT 64
#define L_CH  8
#define W_UP  6
#define S_TOT (W_UP + 9)         // 15 iterations: head at s in [W+1, W+8]
#define ST_H  552                // shorts; 16B-aligned rows
#define ST_U  72

typedef __attribute__((ext_vector_type(8)))  short short8;   // 8 bf16
typedef __attribute__((ext_vector_type(4)))  float f32x4;
typedef __attribute__((ext_vector_type(16))) float f32x16;

__device__ __forceinline__ unsigned short f2bf(float f) {
  union { float f; unsigned u; } v; v.f = f;
  return (unsigned short)((v.u + 0x7FFFu + ((v.u >> 16) & 1u)) >> 16);  // RNE
}
__device__ __forceinline__ unsigned pack2bf(float a, float b) {
  return (unsigned)f2bf(a) | ((unsigned)f2bf(b) << 16);
}
__device__ __forceinline__ float tanh_fast(float x) {
  float e = __expf(2.f * x);
  float r = __builtin_amdgcn_rcpf(e + 1.f);
  return __builtin_fmaf(-2.f, r, 1.f);
}

#define MFMA32(a, b, c) __builtin_amdgcn_mfma_f32_32x32x16_bf16(a, b, c, 0, 0, 0)
#define MFMA16(a, b, c) __builtin_amdgcn_mfma_f32_16x16x32_bf16(a, b, c, 0, 0, 0)

// ---- pack ------------------------------------------------------------------
// 32x32x16 A-op: lane holds A[m = 32*mt + (L&31)][k = 16*kk + 8*(L>>5) + j]
// Apk  [kk=33][mt=16][lane][8] : kk<32 -> W_hh[m][k]*om[k]^2 ; kk=32 -> bias col
// WihPk[kk= 4][mt=16][lane][8] : W_ih[m][k]
// 16x16x32 A-op: lane holds A[m = 16*ot + (L&15)][k = 32*kk + 8*(L>>4) + j]
// WlinPk[kk=17][ot=4][lane][8] : kk<16 -> W_lin[m][k] ; kk=16 -> b_lin col
__global__ __launch_bounds__(256) void pack_kernel(
    const float* __restrict__ W_ih, const float* __restrict__ W_hh,
    const float* __restrict__ b_ih, const float* __restrict__ b_hh,
    const float* __restrict__ omega, const float* __restrict__ W_lin,
    const float* __restrict__ b_lin,
    unsigned short* __restrict__ Apk, unsigned short* __restrict__ WihPk,
    unsigned short* __restrict__ WlinPk)
{
  const int id = blockIdx.x * 256 + threadIdx.x;
  if (id < 33792) {                        // ---- Apk
    const int kk = id >> 10, mt = (id >> 6) & 15, lane = id & 63;
    const int r = lane & 31, h5 = lane >> 5;
    const int m = mt * 32 + r;
    unsigned short* dst = Apk + (size_t)id * 8;
    if (kk < 32) {
      const int k0 = kk * 16 + h5 * 8;
      #pragma unroll
      for (int j = 0; j < 8; j++) {
        const float om = omega[k0 + j];
        dst[j] = f2bf(W_hh[(size_t)m * H_DIM + k0 + j] * om * om);
      }
    } else {
      #pragma unroll
      for (int j = 0; j < 8; j++) {
        const int kp = h5 * 8 + j;
        dst[j] = (kp == 0) ? f2bf(b_ih[m] + b_hh[m]) : 0;
      }
    }
  } else if (id < 37888) {                 // ---- WihPk
    const int id2 = id - 33792;
    const int kk = id2 >> 10, mt = (id2 >> 6) & 15, lane = id2 & 63;
    const int r = lane & 31, h5 = lane >> 5;
    const int m = mt * 32 + r, k0 = kk * 16 + h5 * 8;
    unsigned short* dst = WihPk + (size_t)id2 * 8;
    #pragma unroll
    for (int j = 0; j < 8; j++) dst[j] = f2bf(W_ih[(size_t)m * N_IN + k0 + j]);
  } else if (id < 42240) {                 // ---- WlinPk
    const int id3 = id - 37888;
    const int kk = id3 >> 8, ot = (id3 >> 6) & 3, lane = id3 & 63;
    const int c = lane & 15, q = lane >> 4;
    const int m = ot * 16 + c;
    unsigned short* dst = WlinPk + (size_t)id3 * 8;
    if (kk < 16) {
      const int k0 = kk * 32 + q * 8;
      #pragma unroll
      for (int j = 0; j < 8; j++) dst[j] = f2bf(W_lin[(size_t)m * H_DIM + k0 + j]);
    } else {
      #pragma unroll
      for (int j = 0; j < 8; j++) dst[j] = (q * 8 + j == 0) ? f2bf(b_lin[m]) : 0;
    }
  }
}

// ---- main time-parallel recurrence -----------------------------------------
// 256 blocks x 768 threads (12 waves, 1 block/CU, 3 waves/SIMD -> 170 regs).
// Waves 0-7: main GEMM (2 mt x 2 nt of 32x32). Waves 8-11: head, then u staging.
__global__ __launch_bounds__(768, 3) void rnn_kernel(
    const float* __restrict__ u,
    const unsigned short* __restrict__ Apk,
    const unsigned short* __restrict__ WihPk,
    const unsigned short* __restrict__ WlinPk,
    float* __restrict__ out)
{
  __shared__ __align__(16) unsigned short h_buf[2][64][ST_H];  // 141,312 B
  __shared__ __align__(16) unsigned short u_buf[2][64][ST_U];  //  18,432 B

  const int tid = threadIdx.x;
  const int w = tid >> 6, lane = tid & 63;
  const int rcol = lane & 31, h5 = lane >> 5;       // 32x32 indexing
  const int c = lane & 15, q = lane >> 4;           // 16x16 indexing (head)
  const int t0 = blockIdx.x * L_CH;

  // init: zero both h buffers (incl. ext cols), stage u for iteration 0
  for (int i = tid; i < 2 * 64 * ST_H / 2; i += 768) ((unsigned*)h_buf)[i] = 0;
  if (tid < 256) {
    int t = t0 - W_UP; if (t < 0) t = 0;
    const int row = tid >> 2, cb = (tid & 3) * 16;
    const float* src = u + ((size_t)row * T_LEN + t) * N_IN + cb;
    unsigned* d = (unsigned*)&u_buf[0][row][cb];
    #pragma unroll
    for (int p = 0; p < 8; p++) d[p] = pack2bf(src[2 * p], src[2 * p + 1]);
  }
  __syncthreads();
  if (tid < 128) h_buf[tid >> 6][tid & 63][H_DIM] = 0x3F80;  // bf16 1.0 (bias row)
  __syncthreads();

  for (int s = 0; s < S_TOT; s++) {
    const int cur = s & 1, nxt = cur ^ 1;

    if (w < 8) {
      if (s < S_TOT - 1) {
        f32x16 acc[2][2];
        #pragma unroll
        for (int i = 0; i < 2; i++)
          #pragma unroll
          for (int j = 0; j < 2; j++)
            acc[i][j] = (f32x16)(0.f);

        // ---- A(L2) x h(LDS): K = 528 (incl. bias col) ----
        const unsigned short* ap = Apk + ((size_t)(2 * w) * 64 + lane) * 8;
        #pragma unroll 4
        for (int kk = 0; kk < 33; kk++) {
          const short8 hf0 = *(const short8*)&h_buf[cur][rcol][kk * 16 + h5 * 8];
          const short8 hf1 = *(const short8*)&h_buf[cur][32 + rcol][kk * 16 + h5 * 8];
          const short8 a0 = *(const short8*)(ap + (size_t)kk * 8192);
          const short8 a1 = *(const short8*)(ap + (size_t)kk * 8192 + 512);
          acc[0][0] = MFMA32(a0, hf0, acc[0][0]);
          acc[1][0] = MFMA32(a1, hf0, acc[1][0]);
          acc[0][1] = MFMA32(a0, hf1, acc[0][1]);
          acc[1][1] = MFMA32(a1, hf1, acc[1][1]);
        }
        // ---- + W_ih(L2) x u(LDS): K = 64 ----
        const unsigned short* wp = WihPk + ((size_t)(2 * w) * 64 + lane) * 8;
        #pragma unroll
        for (int kk = 0; kk < 4; kk++) {
          const short8 uf0 = *(const short8*)&u_buf[cur][rcol][kk * 16 + h5 * 8];
          const short8 uf1 = *(const short8*)&u_buf[cur][32 + rcol][kk * 16 + h5 * 8];
          const short8 a0 = *(const short8*)(wp + (size_t)kk * 8192);
          const short8 a1 = *(const short8*)(wp + (size_t)kk * 8192 + 512);
          acc[0][0] = MFMA32(a0, uf0, acc[0][0]);
          acc[1][0] = MFMA32(a1, uf0, acc[1][0]);
          acc[0][1] = MFMA32(a0, uf1, acc[0][1]);
          acc[1][1] = MFMA32(a1, uf1, acc[1][1]);
        }

        // ---- epilogue: h_new = tanh(acc) -> h_buf[nxt]
        // 32x32 D: col = lane&31, row = (reg&3) + 8*(reg>>2) + 4*(lane>>5)
        #pragma unroll
        for (int mtl = 0; mtl < 2; mtl++) {
          #pragma unroll
          for (int ntl = 0; ntl < 2; ntl++) {
            const f32x16 v = acc[mtl][ntl];
            unsigned short* rowp =
                &h_buf[nxt][ntl * 32 + rcol][(2 * w + mtl) * 32 + 4 * h5];
            #pragma unroll
            for (int jq = 0; jq < 4; jq++) {
              unsigned* d = (unsigned*)(rowp + 8 * jq);
              d[0] = pack2bf(tanh_fast(v[4 * jq]),     tanh_fast(v[4 * jq + 1]));
              d[1] = pack2bf(tanh_fast(v[4 * jq + 2]), tanh_fast(v[4 * jq + 3]));
            }
          }
        }
      }
    } else {
      // ---- head (waves 8-11): out_t = W_lin_ext x h^{(s)} (reads h_buf[cur]) ----
      if (s >= W_UP + 1) {
        const int t = t0 + s - W_UP - 1;
        const int ot = w - 8;
        f32x4 hacc[4];
        #pragma unroll
        for (int bt = 0; bt < 4; bt++) hacc[bt] = (f32x4){0.f, 0.f, 0.f, 0.f};
        const unsigned short* lp = WlinPk + ((size_t)ot * 64 + lane) * 8;
        #pragma unroll 4
        for (int kk = 0; kk < 17; kk++) {
          const short8 a = *(const short8*)(lp + (size_t)kk * 2048);
          #pragma unroll
          for (int bt = 0; bt < 4; bt++) {
            const short8 hf = *(const short8*)&h_buf[cur][bt * 16 + c][kk * 32 + q * 8];
            hacc[bt] = MFMA16(a, hf, hacc[bt]);
          }
        }
        #pragma unroll
        for (int bt = 0; bt < 4; bt++) {
          float* op = out + ((size_t)(bt * 16 + c) * T_LEN + t) * N_OUT + ot * 16 + q * 4;
          *(f32x4*)op = hacc[bt];
        }
      }
      // ---- u staging (waves 8-11): u_{tau(s+1)} -> u_buf[nxt] ----
      if (s < S_TOT - 2) {
        int tn = t0 - W_UP + s + 1;
        tn = tn < 0 ? 0 : (tn > T_LEN - 1 ? T_LEN - 1 : tn);
        const int ht = (w - 8) * 64 + lane;           // 0..255
        const int row = ht >> 2, cb = (ht & 3) * 16;  // 16 floats/thread
        const float* src = u + ((size_t)row * T_LEN + tn) * N_IN + cb;
        unsigned* d = (unsigned*)&u_buf[nxt][row][cb];
        #pragma unroll
        for (int p = 0; p < 8; p++) d[p] = pack2bf(src[2 * p], src[2 * p + 1]);
      }
    }
    __syncthreads();
  }
}

extern "C" void kernel_launch(void* const* d_in, const int* in_sizes, int n_in,
                              void* d_out, int out_size, void* d_ws, size_t ws_size,
                              hipStream_t stream) {
  const float* u     = (const float*)d_in[0];
  const float* W_ih  = (const float*)d_in[1];
  const float* W_hh  = (const float*)d_in[2];
  const float* b_ih  = (const float*)d_in[3];
  const float* b_hh  = (const float*)d_in[4];
  const float* omega = (const float*)d_in[5];
  const float* W_lin = (const float*)d_in[6];
  const float* b_lin = (const float*)d_in[7];
  float* out = (float*)d_out;

  unsigned short* Apk    = (unsigned short*)d_ws;            // 33*16*64*8 shorts
  unsigned short* WihPk  = Apk + (size_t)33 * 16 * 64 * 8;   // 4*16*64*8
  unsigned short* WlinPk = WihPk + (size_t)4 * 16 * 64 * 8;  // 17*4*64*8

  pack_kernel<<<165, 256, 0, stream>>>(W_ih, W_hh, b_ih, b_hh, omega, W_lin,
                                       b_lin, Apk, WihPk, WlinPk);
  rnn_kernel<<<T_LEN / L_CH, 768, 0, stream>>>(u, Apk, WihPk, WlinPk, out);
}

// Round 6
// 383.790 us; speedup vs baseline: 1.2180x; 1.0564x over previous
//
#include <hip/hip_runtime.h>

// rnn_lyapunov: B=64,T=2048,NIN=64,NH=512,NOUT=64
// Time-parallel chunked RNN, W=6 warmup (contraction ||A||<=0.36).
// R6: R5's minimal-traffic GEMM config (32x32x16, 8 waves x 2mt x 2nt,
// bias folded as K-column) but 512 threads / 8 waves / __launch_bounds__(512,2)
// -> 256-reg cap: 64 AGPR acc + ~130 VGPR fits with slack, scratch spill
// (R4/R5's 400MB HBM anomaly) becomes impossible. Head + u staging fold back
// into the main waves after the single per-step barrier.

#define T_LEN 2048
#define H_DIM 512
#define N_IN  64
#define N_OUT 64
#define L_CH  8
#define W_UP  6
#define S_TOT (W_UP + 8)         // 14 steps; head after barrier at s in [W, W+7]
#define ST_H  552                // shorts; 16B-aligned rows; holds K=528 ext cols
#define ST_U  72

typedef __attribute__((ext_vector_type(8)))  short short8;   // 8 bf16
typedef __attribute__((ext_vector_type(4)))  float f32x4;
typedef __attribute__((ext_vector_type(16))) float f32x16;

__device__ __forceinline__ unsigned short f2bf(float f) {
  union { float f; unsigned u; } v; v.f = f;
  return (unsigned short)((v.u + 0x7FFFu + ((v.u >> 16) & 1u)) >> 16);  // RNE
}
__device__ __forceinline__ unsigned pack2bf(float a, float b) {
  return (unsigned)f2bf(a) | ((unsigned)f2bf(b) << 16);
}
__device__ __forceinline__ float tanh_fast(float x) {
  float e = __expf(2.f * x);
  float r = __builtin_amdgcn_rcpf(e + 1.f);
  return __builtin_fmaf(-2.f, r, 1.f);
}

#define MFMA32(a, b, c) __builtin_amdgcn_mfma_f32_32x32x16_bf16(a, b, c, 0, 0, 0)
#define MFMA16(a, b, c) __builtin_amdgcn_mfma_f32_16x16x32_bf16(a, b, c, 0, 0, 0)

// ---- pack (unchanged from R5, numerically validated) -----------------------
// 32x32x16 A-op: lane holds A[m = 32*mt + (L&31)][k = 16*kk + 8*(L>>5) + j]
// Apk  [kk=33][mt=16][lane][8] : kk<32 -> W_hh[m][k]*om[k]^2 ; kk=32 -> bias col
// WihPk[kk= 4][mt=16][lane][8] : W_ih[m][k]
// 16x16x32 A-op: lane holds A[m = 16*ot + (L&15)][k = 32*kk + 8*(L>>4) + j]
// WlinPk[kk=17][ot=4][lane][8] : kk<16 -> W_lin[m][k] ; kk=16 -> b_lin col
__global__ __launch_bounds__(256) void pack_kernel(
    const float* __restrict__ W_ih, const float* __restrict__ W_hh,
    const float* __restrict__ b_ih, const float* __restrict__ b_hh,
    const float* __restrict__ omega, const float* __restrict__ W_lin,
    const float* __restrict__ b_lin,
    unsigned short* __restrict__ Apk, unsigned short* __restrict__ WihPk,
    unsigned short* __restrict__ WlinPk)
{
  const int id = blockIdx.x * 256 + threadIdx.x;
  if (id < 33792) {                        // ---- Apk
    const int kk = id >> 10, mt = (id >> 6) & 15, lane = id & 63;
    const int r = lane & 31, h5 = lane >> 5;
    const int m = mt * 32 + r;
    unsigned short* dst = Apk + (size_t)id * 8;
    if (kk < 32) {
      const int k0 = kk * 16 + h5 * 8;
      #pragma unroll
      for (int j = 0; j < 8; j++) {
        const float om = omega[k0 + j];
        dst[j] = f2bf(W_hh[(size_t)m * H_DIM + k0 + j] * om * om);
      }
    } else {
      #pragma unroll
      for (int j = 0; j < 8; j++) {
        const int kp = h5 * 8 + j;
        dst[j] = (kp == 0) ? f2bf(b_ih[m] + b_hh[m]) : 0;
      }
    }
  } else if (id < 37888) {                 // ---- WihPk
    const int id2 = id - 33792;
    const int kk = id2 >> 10, mt = (id2 >> 6) & 15, lane = id2 & 63;
    const int r = lane & 31, h5 = lane >> 5;
    const int m = mt * 32 + r, k0 = kk * 16 + h5 * 8;
    unsigned short* dst = WihPk + (size_t)id2 * 8;
    #pragma unroll
    for (int j = 0; j < 8; j++) dst[j] = f2bf(W_ih[(size_t)m * N_IN + k0 + j]);
  } else if (id < 42240) {                 // ---- WlinPk
    const int id3 = id - 37888;
    const int kk = id3 >> 8, ot = (id3 >> 6) & 3, lane = id3 & 63;
    const int c = lane & 15, q = lane >> 4;
    const int m = ot * 16 + c;
    unsigned short* dst = WlinPk + (size_t)id3 * 8;
    if (kk < 16) {
      const int k0 = kk * 32 + q * 8;
      #pragma unroll
      for (int j = 0; j < 8; j++) dst[j] = f2bf(W_lin[(size_t)m * H_DIM + k0 + j]);
    } else {
      #pragma unroll
      for (int j = 0; j < 8; j++) dst[j] = (q * 8 + j == 0) ? f2bf(b_lin[m]) : 0;
    }
  }
}

// ---- main time-parallel recurrence -----------------------------------------
// 256 blocks x 512 threads (8 waves, 1 block/CU, 2 waves/SIMD -> 256-reg cap).
// All waves: GEMM (2mt x 2nt of 32x32) -> epilogue -> barrier -> head (2 tiles).
__global__ __launch_bounds__(512, 2) void rnn_kernel(
    const float* __restrict__ u,
    const unsigned short* __restrict__ Apk,
    const unsigned short* __restrict__ WihPk,
    const unsigned short* __restrict__ WlinPk,
    float* __restrict__ out)
{
  __shared__ __align__(16) unsigned short h_buf[2][64][ST_H];  // 141,312 B
  __shared__ __align__(16) unsigned short u_buf[2][64][ST_U];  //  18,432 B

  const int tid = threadIdx.x;
  const int w = tid >> 6, lane = tid & 63;
  const int rcol = lane & 31, h5 = lane >> 5;       // 32x32 indexing
  const int c = lane & 15, q = lane >> 4;           // 16x16 indexing (head)
  const int t0 = blockIdx.x * L_CH;
  const int ot = w & 3, bt0 = (w >> 2) * 2;         // head tiles: (ot, bt0/bt0+1)

  // init: zero both h buffers, stage u for step 0, set bias row (col 512 = 1.0)
  for (int i = tid; i < 2 * 64 * ST_H / 2; i += 512) ((unsigned*)h_buf)[i] = 0;
  {
    int t = t0 - W_UP; if (t < 0) t = 0;
    const int row = tid >> 3, cb = (tid & 7) * 8;
    const float* src = u + ((size_t)row * T_LEN + t) * N_IN + cb;
    unsigned* d = (unsigned*)&u_buf[0][row][cb];
    #pragma unroll
    for (int p = 0; p < 4; p++) d[p] = pack2bf(src[2 * p], src[2 * p + 1]);
  }
  __syncthreads();
  if (tid < 128) h_buf[tid >> 6][tid & 63][H_DIM] = 0x3F80;  // bf16 1.0
  __syncthreads();

  for (int s = 0; s < S_TOT; s++) {
    const int cur = s & 1, nxt = cur ^ 1;

    // prefetch next step's u into registers (coalesced, 8 floats/thread)
    float up[8];
    {
      int tn = t0 - W_UP + s + 1;
      tn = tn < 0 ? 0 : (tn > T_LEN - 1 ? T_LEN - 1 : tn);
      const int row = tid >> 3, cb = (tid & 7) * 8;
      const float* src = u + ((size_t)row * T_LEN + tn) * N_IN + cb;
      #pragma unroll
      for (int p = 0; p < 8; p++) up[p] = src[p];
    }

    f32x16 acc00 = (f32x16)(0.f), acc01 = (f32x16)(0.f);
    f32x16 acc10 = (f32x16)(0.f), acc11 = (f32x16)(0.f);

    // ---- A(L2) x h(LDS): K = 528 (incl. bias col) ----
    const unsigned short* ap = Apk + ((size_t)(2 * w) * 64 + lane) * 8;
    #pragma unroll 4
    for (int kk = 0; kk < 33; kk++) {
      const short8 hf0 = *(const short8*)&h_buf[cur][rcol][kk * 16 + h5 * 8];
      const short8 hf1 = *(const short8*)&h_buf[cur][32 + rcol][kk * 16 + h5 * 8];
      const short8 a0 = *(const short8*)(ap + (size_t)kk * 8192);
      const short8 a1 = *(const short8*)(ap + (size_t)kk * 8192 + 512);
      acc00 = MFMA32(a0, hf0, acc00);
      acc10 = MFMA32(a1, hf0, acc10);
      acc01 = MFMA32(a0, hf1, acc01);
      acc11 = MFMA32(a1, hf1, acc11);
    }
    // ---- + W_ih(L2) x u(LDS): K = 64 ----
    const unsigned short* wp = WihPk + ((size_t)(2 * w) * 64 + lane) * 8;
    #pragma unroll
    for (int kk = 0; kk < 4; kk++) {
      const short8 uf0 = *(const short8*)&u_buf[cur][rcol][kk * 16 + h5 * 8];
      const short8 uf1 = *(const short8*)&u_buf[cur][32 + rcol][kk * 16 + h5 * 8];
      const short8 a0 = *(const short8*)(wp + (size_t)kk * 8192);
      const short8 a1 = *(const short8*)(wp + (size_t)kk * 8192 + 512);
      acc00 = MFMA32(a0, uf0, acc00);
      acc10 = MFMA32(a1, uf0, acc10);
      acc01 = MFMA32(a0, uf1, acc01);
      acc11 = MFMA32(a1, uf1, acc11);
    }

    // ---- epilogue: h_new = tanh(acc) -> h_buf[nxt]
    // 32x32 D: col = lane&31, row = (reg&3) + 8*(reg>>2) + 4*(lane>>5)
    #pragma unroll
    for (int mtl = 0; mtl < 2; mtl++) {
      #pragma unroll
      for (int ntl = 0; ntl < 2; ntl++) {
        const f32x16 v = mtl ? (ntl ? acc11 : acc10) : (ntl ? acc01 : acc00);
        unsigned short* rowp =
            &h_buf[nxt][ntl * 32 + rcol][(2 * w + mtl) * 32 + 4 * h5];
        #pragma unroll
        for (int jq = 0; jq < 4; jq++) {
          unsigned* d = (unsigned*)(rowp + 8 * jq);
          d[0] = pack2bf(tanh_fast(v[4 * jq]),     tanh_fast(v[4 * jq + 1]));
          d[1] = pack2bf(tanh_fast(v[4 * jq + 2]), tanh_fast(v[4 * jq + 3]));
        }
      }
    }
    {
      const int row = tid >> 3, cb = (tid & 7) * 8;
      unsigned* d = (unsigned*)&u_buf[nxt][row][cb];
      #pragma unroll
      for (int p = 0; p < 4; p++) d[p] = pack2bf(up[2 * p], up[2 * p + 1]);
    }
    __syncthreads();   // single barrier: [nxt] visible; [cur] free for reuse

    // ---- head: out_t = W_lin_ext x h^{(tau(s))} (reads h_buf[nxt]) ----
    if (s >= W_UP) {
      const int t = t0 + s - W_UP;
      f32x4 hacc0 = (f32x4){0.f, 0.f, 0.f, 0.f};
      f32x4 hacc1 = (f32x4){0.f, 0.f, 0.f, 0.f};
      const unsigned short* lp = WlinPk + ((size_t)ot * 64 + lane) * 8;
      #pragma unroll 4
      for (int kk = 0; kk < 17; kk++) {
        const short8 a = *(const short8*)(lp + (size_t)kk * 2048);
        const short8 hb0 = *(const short8*)&h_buf[nxt][bt0 * 16 + c][kk * 32 + q * 8];
        const short8 hb1 = *(const short8*)&h_buf[nxt][(bt0 + 1) * 16 + c][kk * 32 + q * 8];
        hacc0 = MFMA16(a, hb0, hacc0);
        hacc1 = MFMA16(a, hb1, hacc1);
      }
      float* op0 = out + ((size_t)(bt0 * 16 + c) * T_LEN + t) * N_OUT + ot * 16 + q * 4;
      float* op1 = out + ((size_t)((bt0 + 1) * 16 + c) * T_LEN + t) * N_OUT + ot * 16 + q * 4;
      *(f32x4*)op0 = hacc0;
      *(f32x4*)op1 = hacc1;
    }
  }
}

extern "C" void kernel_launch(void* const* d_in, const int* in_sizes, int n_in,
                              void* d_out, int out_size, void* d_ws, size_t ws_size,
                              hipStream_t stream) {
  const float* u     = (const float*)d_in[0];
  const float* W_ih  = (const float*)d_in[1];
  const float* W_hh  = (const float*)d_in[2];
  const float* b_ih  = (const float*)d_in[3];
  const float* b_hh  = (const float*)d_in[4];
  const float* omega = (const float*)d_in[5];
  const float* W_lin = (const float*)d_in[6];
  const float* b_lin = (const float*)d_in[7];
  float* out = (float*)d_out;

  unsigned short* Apk    = (unsigned short*)d_ws;            // 33*16*64*8 shorts
  unsigned short* WihPk  = Apk + (size_t)33 * 16 * 64 * 8;   // 4*16*64*8
  unsigned short* WlinPk = WihPk + (size_t)4 * 16 * 64 * 8;  // 17*4*64*8

  pack_kernel<<<165, 256, 0, stream>>>(W_ih, W_hh, b_ih, b_hh, omega, W_lin,
                                       b_lin, Apk, WihPk, WlinPk);
  rnn_kernel<<<T_LEN / L_CH, 512, 0, stream>>>(u, Apk, WihPk, WlinPk, out);
}

// Round 7
// 238.247 us; speedup vs baseline: 1.9620x; 1.6109x over previous
//
#include <hip/hip_runtime.h>

// rnn_lyapunov: B=64,T=2048,NIN=64,NH=512,NOUT=64
// Time-parallel chunked RNN, W=6 warmup (contraction ||A||<=0.36).
// R7: revert to the proven-clean R3 kernel shape (16x16x32 MFMA, f32x4 accs,
// 1024 thr, VGPR~60, FETCH 37MB) — every f32x16/32x32 variant (R4-R6) showed
// a 400-600MB HBM-traffic anomaly regardless of reg headroom. Only change
// vs R3: W_UP 8->6 (validated at absmax 0.0156 in R5/R6), 16->14 steps.

#define T_LEN 2048
#define H_DIM 512
#define N_IN  64
#define N_OUT 64
#define L_CH  8                  // output steps per chunk
#define W_UP  6                  // warmup steps per chunk
#define S_TOT (W_UP + 8)         // 14 steps per chunk
#define ST_H  520                // h_buf row stride (shorts): 16B-aligned, bank-uniform
#define ST_U  72                 // u_buf row stride (shorts): 16B-aligned

typedef __attribute__((ext_vector_type(8))) short short8;   // 8 bf16 in 4 VGPRs
typedef __attribute__((ext_vector_type(4))) float f32x4;

__device__ __forceinline__ unsigned short f2bf(float f) {
  union { float f; unsigned u; } v; v.f = f;
  return (unsigned short)((v.u + 0x7FFFu + ((v.u >> 16) & 1u)) >> 16);  // RNE
}
__device__ __forceinline__ unsigned pack2bf(float a, float b) {
  return (unsigned)f2bf(a) | ((unsigned)f2bf(b) << 16);
}
__device__ __forceinline__ float tanh_fast(float x) {
  float e = __expf(2.f * x);
  float r = __builtin_amdgcn_rcpf(e + 1.f);
  return __builtin_fmaf(-2.f, r, 1.f);   // +inf: r=0 -> 1; -inf: r=1 -> -1
}

#define MFMA(a, b, acc) __builtin_amdgcn_mfma_f32_16x16x32_bf16(a, b, acc, 0, 0, 0)

// ---- pack weights into MFMA A-operand fragment layout (identical to R3) ----
// A-frag 16x16x32: lane L holds A[m = 16*mt + (L&15)][k = 32*kk + 8*(L>>4) + j]
// Apk  [kk=16][mt=32][lane][8] : W_hh[m][k]*omega[k]^2   (m,k < 512)
// WihPk[kk= 2][mt=32][lane][8] : W_ih[m][k]              (m<512, k<64)
// WlinPk[kk=16][mt=4][lane][8] : W_lin[m][k]             (m<64, k<512)
__global__ __launch_bounds__(256) void pack_kernel(
    const float* __restrict__ W_ih, const float* __restrict__ W_hh,
    const float* __restrict__ omega, const float* __restrict__ W_lin,
    unsigned short* __restrict__ Apk, unsigned short* __restrict__ WihPk,
    unsigned short* __restrict__ WlinPk)
{
  __shared__ unsigned short Lh[512][40];     // 40: even-8 stride, 16B-aligned rows
  const int tid = threadIdx.x, bid = blockIdx.x;
  const int l32 = tid & 31, nr = tid >> 5;

  if (bid < 16) {                            // ---- A: kk = bid
    const int k0 = bid * 32;
    const float om = omega[k0 + l32];
    const float om2 = om * om;
    for (int n = nr; n < 512; n += 8)
      Lh[n][l32] = f2bf(W_hh[(size_t)n * 512 + k0 + l32] * om2);
    __syncthreads();
    const int mt = tid >> 3, lane0 = (tid & 7) * 8;
    unsigned short* dst = Apk + (size_t)bid * 16384 + (size_t)tid * 64;
    #pragma unroll
    for (int l = 0; l < 8; l++) {
      const int lane = lane0 + l, c = lane & 15, q = lane >> 4;
      *(short8*)(dst + l * 8) = *(const short8*)&Lh[mt * 16 + c][q * 8];
    }
  } else if (bid < 18) {                     // ---- W_ih: kk = bid-16
    const int kk = bid - 16, k0 = kk * 32;
    for (int n = nr; n < 512; n += 8)
      Lh[n][l32] = f2bf(W_ih[(size_t)n * 64 + k0 + l32]);
    __syncthreads();
    const int mt = tid >> 3, lane0 = (tid & 7) * 8;
    unsigned short* dst = WihPk + (size_t)kk * 16384 + (size_t)tid * 64;
    #pragma unroll
    for (int l = 0; l < 8; l++) {
      const int lane = lane0 + l, c = lane & 15, q = lane >> 4;
      *(short8*)(dst + l * 8) = *(const short8*)&Lh[mt * 16 + c][q * 8];
    }
  } else {                                   // ---- W_lin: kk = bid-18
    const int kk = bid - 18, k0 = kk * 32;
    for (int n = nr; n < 64; n += 8)
      Lh[n][l32] = f2bf(W_lin[(size_t)n * 512 + k0 + l32]);
    __syncthreads();
    const int mt = tid >> 6, lane = tid & 63, c = lane & 15, q = lane >> 4;
    unsigned short* dst = WlinPk + (size_t)kk * 2048 + (size_t)tid * 8;
    *(short8*)dst = *(const short8*)&Lh[mt * 16 + c][q * 8];
  }
}

// ---- main time-parallel recurrence kernel (R3 shape) ------------------------
// 256 blocks (1 chunk, full batch M=64), 1024 threads = 16 waves (1 block/CU).
// Wave w owns hidden m-tiles {2w, 2w+1}; all 4 batch n-tiles.
// One barrier per step: GEMM reads h_buf[cur], epilogue writes h_buf[nxt].
__global__ __launch_bounds__(1024, 4) void rnn_kernel(
    const float* __restrict__ u, const float* __restrict__ b_ih,
    const float* __restrict__ b_hh, const float* __restrict__ b_lin,
    const unsigned short* __restrict__ Apk,
    const unsigned short* __restrict__ WihPk,
    const unsigned short* __restrict__ WlinPk,
    float* __restrict__ out)
{
  __shared__ __align__(16) unsigned short h_buf[2][64][ST_H];  // 133,120 B
  __shared__ __align__(16) unsigned short u_buf[2][64][ST_U];  //  18,432 B

  const int tid = threadIdx.x;
  const int w = tid >> 6, lane = tid & 63, q = lane >> 4, c = lane & 15;
  const int t0 = blockIdx.x * L_CH;

  // biases in registers: lane's 4 D-rows are consecutive hidden/out indices
  f32x4 bsum[2];
  #pragma unroll
  for (int mt = 0; mt < 2; mt++) {
    const int n0 = (2 * w + mt) * 16 + q * 4;
    bsum[mt] = *(const f32x4*)(b_ih + n0) + *(const f32x4*)(b_hh + n0);
  }
  const int ot = w & 3, bth = w >> 2;        // head: out-tile, batch-tile
  const f32x4 blin4 = *(const f32x4*)(b_lin + ot * 16 + q * 4);

  for (int i = tid; i < 64 * ST_H / 2; i += 1024) ((unsigned*)h_buf[0])[i] = 0;
  {    // stage u for step 0: t_in(0) = max(t0 - W, 0)
    int t = t0 - W_UP; if (t < 0) t = 0;
    const int row = tid >> 4, cb = (tid & 15) * 4;
    const float* src = u + ((size_t)row * T_LEN + t) * N_IN + cb;
    unsigned* d = (unsigned*)&u_buf[0][row][cb];
    d[0] = pack2bf(src[0], src[1]); d[1] = pack2bf(src[2], src[3]);
  }
  __syncthreads();

  f32x4 acc[2][4];

  for (int s = 0; s < S_TOT; s++) {
    const int cur = s & 1, nxt = cur ^ 1;

    // prefetch next step's u into registers (coalesced dwordx4)
    float up0, up1, up2, up3;
    {
      int tn = t0 - W_UP + s + 1;
      tn = tn < 0 ? 0 : (tn > T_LEN - 1 ? T_LEN - 1 : tn);
      const int row = tid >> 4, cb = (tid & 15) * 4;
      const float* src = u + ((size_t)row * T_LEN + tn) * N_IN + cb;
      up0 = src[0]; up1 = src[1]; up2 = src[2]; up3 = src[3];
    }

    #pragma unroll
    for (int mt = 0; mt < 2; mt++)
      #pragma unroll
      for (int bt = 0; bt < 4; bt++)
        acc[mt][bt] = (f32x4){0.f, 0.f, 0.f, 0.f};

    // ---- A(weights, L2-stream) x h(LDS): K = 512 ----
    {
      const unsigned short* apA = Apk + ((size_t)(2 * w) * 64 + lane) * 8;
      #pragma unroll 4
      for (int kk = 0; kk < 16; kk++) {
        short8 hf[4];
        #pragma unroll
        for (int bt = 0; bt < 4; bt++)
          hf[bt] = *(const short8*)&h_buf[cur][bt * 16 + c][kk * 32 + q * 8];
        const short8 a0 = *(const short8*)(apA + (size_t)kk * 16384);
        const short8 a1 = *(const short8*)(apA + (size_t)kk * 16384 + 512);
        #pragma unroll
        for (int bt = 0; bt < 4; bt++) {
          acc[0][bt] = MFMA(a0, hf[bt], acc[0][bt]);
          acc[1][bt] = MFMA(a1, hf[bt], acc[1][bt]);
        }
      }
    }
    // ---- + W_ih x u_t: K = 64, same accumulators ----
    {
      const unsigned short* wpA = WihPk + ((size_t)(2 * w) * 64 + lane) * 8;
      #pragma unroll
      for (int kk = 0; kk < 2; kk++) {
        short8 uf[4];
        #pragma unroll
        for (int bt = 0; bt < 4; bt++)
          uf[bt] = *(const short8*)&u_buf[cur][bt * 16 + c][kk * 32 + q * 8];
        const short8 a0 = *(const short8*)(wpA + (size_t)kk * 16384);
        const short8 a1 = *(const short8*)(wpA + (size_t)kk * 16384 + 512);
        #pragma unroll
        for (int bt = 0; bt < 4; bt++) {
          acc[0][bt] = MFMA(a0, uf[bt], acc[0][bt]);
          acc[1][bt] = MFMA(a1, uf[bt], acc[1][bt]);
        }
      }
    }

    // ---- epilogue: h_new = tanh(acc + bias); lane writes 4 consecutive
    // hidden cols per (mt,bt) -> b64 LDS writes ----
    #pragma unroll
    for (int mt = 0; mt < 2; mt++) {
      #pragma unroll
      for (int bt = 0; bt < 4; bt++) {
        const unsigned lo = pack2bf(tanh_fast(acc[mt][bt][0] + bsum[mt][0]),
                                    tanh_fast(acc[mt][bt][1] + bsum[mt][1]));
        const unsigned hi = pack2bf(tanh_fast(acc[mt][bt][2] + bsum[mt][2]),
                                    tanh_fast(acc[mt][bt][3] + bsum[mt][3]));
        unsigned* d = (unsigned*)&h_buf[nxt][bt * 16 + c][(2 * w + mt) * 16 + q * 4];
        d[0] = lo; d[1] = hi;
      }
    }
    {
      const int row = tid >> 4, cb = (tid & 15) * 4;
      unsigned* d = (unsigned*)&u_buf[nxt][row][cb];
      d[0] = pack2bf(up0, up1); d[1] = pack2bf(up2, up3);
    }
    __syncthreads();   // single barrier: [nxt] visible to head + next GEMM

    // ---- head: out_t = W_lin x h_t + b_lin; lane stores 4 consecutive
    // out cols -> global dwordx4 ----
    if (s >= W_UP) {
      const int t = t0 + s - W_UP;
      f32x4 hacc = (f32x4){0.f, 0.f, 0.f, 0.f};
      const unsigned short* lpA = WlinPk + ((size_t)ot * 64 + lane) * 8;
      #pragma unroll 4
      for (int kk = 0; kk < 16; kk++) {
        const short8 hfr = *(const short8*)&h_buf[nxt][bth * 16 + c][kk * 32 + q * 8];
        const short8 a = *(const short8*)(lpA + (size_t)kk * 2048);
        hacc = MFMA(a, hfr, hacc);
      }
      const f32x4 res = hacc + blin4;
      float* op = out + ((size_t)(bth * 16 + c) * T_LEN + t) * N_OUT + ot * 16 + q * 4;
      *(f32x4*)op = res;
    }
  }
}

extern "C" void kernel_launch(void* const* d_in, const int* in_sizes, int n_in,
                              void* d_out, int out_size, void* d_ws, size_t ws_size,
                              hipStream_t stream) {
  const float* u     = (const float*)d_in[0];
  const float* W_ih  = (const float*)d_in[1];
  const float* W_hh  = (const float*)d_in[2];
  const float* b_ih  = (const float*)d_in[3];
  const float* b_hh  = (const float*)d_in[4];
  const float* omega = (const float*)d_in[5];
  const float* W_lin = (const float*)d_in[6];
  const float* b_lin = (const float*)d_in[7];
  float* out = (float*)d_out;

  unsigned short* Apk    = (unsigned short*)d_ws;                 // 512*512 bf16
  unsigned short* WihPk  = Apk + (size_t)H_DIM * H_DIM;           // 512*64
  unsigned short* WlinPk = WihPk + (size_t)H_DIM * N_IN;          // 64*512

  pack_kernel<<<34, 256, 0, stream>>>(W_ih, W_hh, omega, W_lin, Apk, WihPk, WlinPk);
  rnn_kernel<<<T_LEN / L_CH, 1024, 0, stream>>>(u, b_ih, b_hh, b_lin,
                                                Apk, WihPk, WlinPk, out);
}

// Round 8
// 233.673 us; speedup vs baseline: 2.0004x; 1.0196x over previous
//
#include <hip/hip_runtime.h>

// rnn_lyapunov: B=64,T=2048,NIN=64,NH=512,NOUT=64
// Time-parallel chunked RNN, W=5 warmup (contraction ||A||~0.3).
// R8 (from R7): head merged into main GEMM as 4 extra A-tiles on waves 12-15
// (reuses the already-loaded h B-fragments -> head LDS reads = 0, no serial
// head phase); W_UP 6->5; tanh via 2*log2e prescaled weights + exp2+rcp;
// HW v_cvt_pk_bf16_f32 when available. 16x16x32 MFMA / f32x4 accs only
// (f32x16 shapes trigger a 400-600MB HBM anomaly — R4-R6).

#define T_LEN 2048
#define H_DIM 512
#define N_IN  64
#define N_OUT 64
#define L_CH  8
#define W_UP  5
#define S_FULL (W_UP + 8)        // 13 full steps (s=0..12) + final head-only
#define ST_H  520                // h_buf row stride (shorts): 16B-aligned
#define ST_U  72
#define K2f   2.8853900817779268f   // 2*log2(e), folded into Apk/WihPk/bias

typedef __attribute__((ext_vector_type(8))) short short8;   // 8 bf16 in 4 VGPRs
typedef __attribute__((ext_vector_type(4))) float f32x4;

__device__ __forceinline__ unsigned short f2bf(float f) {
  union { float f; unsigned u; } v; v.f = f;
  return (unsigned short)((v.u + 0x7FFFu + ((v.u >> 16) & 1u)) >> 16);  // RNE
}

#if __has_builtin(__builtin_amdgcn_cvt_pk_bf16_f32)
__device__ __forceinline__ unsigned pack2bf(float a, float b) {
  auto r = __builtin_amdgcn_cvt_pk_bf16_f32(a, b);
  unsigned u; __builtin_memcpy(&u, &r, 4);
  return u;
}
#else
__device__ __forceinline__ unsigned pack2bf(float a, float b) {
  return (unsigned)f2bf(a) | ((unsigned)f2bf(b) << 16);
}
#endif

#if __has_builtin(__builtin_amdgcn_exp2f)
#define EXP2(x) __builtin_amdgcn_exp2f(x)
#else
#define EXP2(x) exp2f(x)
#endif

// z = 2*log2(e)*x (prescale in weights): tanh(x) = 1 - 2/(2^z + 1)
__device__ __forceinline__ float tanh_z(float z) {
  float r = __builtin_amdgcn_rcpf(EXP2(z) + 1.f);
  return __builtin_fmaf(-2.f, r, 1.f);   // z->+inf: 1; z->-inf: -1
}

#define MFMA(a, b, acc) __builtin_amdgcn_mfma_f32_16x16x32_bf16(a, b, acc, 0, 0, 0)

// ---- pack weights into MFMA A-operand fragment layout ----------------------
// A-frag 16x16x32: lane L holds A[m = 16*mt + (L&15)][k = 32*kk + 8*(L>>4) + j]
// Apk  [kk=16][mt=32][lane][8] : K2*W_hh[m][k]*omega[k]^2
// WihPk[kk= 2][mt=32][lane][8] : K2*W_ih[m][k]
// WlinPk[kk=16][mt=4][lane][8] : W_lin[m][k]   (unscaled)
__global__ __launch_bounds__(256) void pack_kernel(
    const float* __restrict__ W_ih, const float* __restrict__ W_hh,
    const float* __restrict__ omega, const float* __restrict__ W_lin,
    unsigned short* __restrict__ Apk, unsigned short* __restrict__ WihPk,
    unsigned short* __restrict__ WlinPk)
{
  __shared__ unsigned short Lh[512][40];
  const int tid = threadIdx.x, bid = blockIdx.x;
  const int l32 = tid & 31, nr = tid >> 5;

  if (bid < 16) {                            // ---- A: kk = bid
    const int k0 = bid * 32;
    const float om = omega[k0 + l32];
    const float om2 = om * om * K2f;
    for (int n = nr; n < 512; n += 8)
      Lh[n][l32] = f2bf(W_hh[(size_t)n * 512 + k0 + l32] * om2);
    __syncthreads();
    const int mt = tid >> 3, lane0 = (tid & 7) * 8;
    unsigned short* dst = Apk + (size_t)bid * 16384 + (size_t)tid * 64;
    #pragma unroll
    for (int l = 0; l < 8; l++) {
      const int lane = lane0 + l, c = lane & 15, q = lane >> 4;
      *(short8*)(dst + l * 8) = *(const short8*)&Lh[mt * 16 + c][q * 8];
    }
  } else if (bid < 18) {                     // ---- W_ih: kk = bid-16
    const int kk = bid - 16, k0 = kk * 32;
    for (int n = nr; n < 512; n += 8)
      Lh[n][l32] = f2bf(W_ih[(size_t)n * 64 + k0 + l32] * K2f);
    __syncthreads();
    const int mt = tid >> 3, lane0 = (tid & 7) * 8;
    unsigned short* dst = WihPk + (size_t)kk * 16384 + (size_t)tid * 64;
    #pragma unroll
    for (int l = 0; l < 8; l++) {
      const int lane = lane0 + l, c = lane & 15, q = lane >> 4;
      *(short8*)(dst + l * 8) = *(const short8*)&Lh[mt * 16 + c][q * 8];
    }
  } else {                                   // ---- W_lin: kk = bid-18
    const int kk = bid - 18, k0 = kk * 32;
    for (int n = nr; n < 64; n += 8)
      Lh[n][l32] = f2bf(W_lin[(size_t)n * 512 + k0 + l32]);
    __syncthreads();
    const int mt = tid >> 6, lane = tid & 63, c = lane & 15, q = lane >> 4;
    unsigned short* dst = WlinPk + (size_t)kk * 2048 + (size_t)tid * 8;
    *(short8*)dst = *(const short8*)&Lh[mt * 16 + c][q * 8];
  }
}

// ---- main time-parallel recurrence kernel ----------------------------------
// 256 blocks (1 chunk, full batch M=64), 1024 threads = 16 waves (1 block/CU).
// Wave w owns hidden A-tiles {2w, 2w+1}; waves 12-15 also own W_lin tile w-12
// (one heavy wave per SIMD). One barrier per step.
__global__ __launch_bounds__(1024, 4) void rnn_kernel(
    const float* __restrict__ u, const float* __restrict__ b_ih,
    const float* __restrict__ b_hh, const float* __restrict__ b_lin,
    const unsigned short* __restrict__ Apk,
    const unsigned short* __restrict__ WihPk,
    const unsigned short* __restrict__ WlinPk,
    float* __restrict__ out)
{
  __shared__ __align__(16) unsigned short h_buf[2][64][ST_H];  // 133,120 B
  __shared__ __align__(16) unsigned short u_buf[2][64][ST_U];  //  18,432 B

  const int tid = threadIdx.x;
  const int w = tid >> 6, lane = tid & 63, q = lane >> 4, c = lane & 15;
  const int t0 = blockIdx.x * L_CH;
  const bool wl = (w >= 12);
  const int lt = w & 3;                      // W_lin tile for waves 12-15

  // biases in registers (prescaled by K2); b_lin raw
  f32x4 bsum[2];
  #pragma unroll
  for (int mt = 0; mt < 2; mt++) {
    const int n0 = (2 * w + mt) * 16 + q * 4;
    const f32x4 bs = *(const f32x4*)(b_ih + n0) + *(const f32x4*)(b_hh + n0);
    bsum[mt] = (f32x4){bs[0] * K2f, bs[1] * K2f, bs[2] * K2f, bs[3] * K2f};
  }
  const f32x4 blin4 = *(const f32x4*)(b_lin + lt * 16 + q * 4);

  for (int i = tid; i < 64 * ST_H / 2; i += 1024) ((unsigned*)h_buf[0])[i] = 0;
  {    // stage u for step 0: tau(0) = max(t0 - W, 0)
    int t = t0 - W_UP; if (t < 0) t = 0;
    const int row = tid >> 4, cb = (tid & 15) * 4;
    const float* src = u + ((size_t)row * T_LEN + t) * N_IN + cb;
    unsigned* d = (unsigned*)&u_buf[0][row][cb];
    d[0] = pack2bf(src[0], src[1]); d[1] = pack2bf(src[2], src[3]);
  }
  __syncthreads();

  f32x4 acc[2][4];

  for (int s = 0; s < S_FULL; s++) {
    const int cur = s & 1, nxt = cur ^ 1;

    // prefetch next step's u into registers (coalesced dwordx4)
    float up0, up1, up2, up3;
    {
      int tn = t0 - W_UP + s + 1;
      tn = tn < 0 ? 0 : (tn > T_LEN - 1 ? T_LEN - 1 : tn);
      const int row = tid >> 4, cb = (tid & 15) * 4;
      const float* src = u + ((size_t)row * T_LEN + tn) * N_IN + cb;
      up0 = src[0]; up1 = src[1]; up2 = src[2]; up3 = src[3];
    }

    #pragma unroll
    for (int mt = 0; mt < 2; mt++)
      #pragma unroll
      for (int bt = 0; bt < 4; bt++)
        acc[mt][bt] = (f32x4){0.f, 0.f, 0.f, 0.f};

    // ---- A(L2) x h(LDS): K = 512; waves 12-15 also accumulate W_lin x h ----
    const unsigned short* apA = Apk + ((size_t)(2 * w) * 64 + lane) * 8;
    if (!wl) {
      #pragma unroll 4
      for (int kk = 0; kk < 16; kk++) {
        short8 hf[4];
        #pragma unroll
        for (int bt = 0; bt < 4; bt++)
          hf[bt] = *(const short8*)&h_buf[cur][bt * 16 + c][kk * 32 + q * 8];
        const short8 a0 = *(const short8*)(apA + (size_t)kk * 16384);
        const short8 a1 = *(const short8*)(apA + (size_t)kk * 16384 + 512);
        #pragma unroll
        for (int bt = 0; bt < 4; bt++) {
          acc[0][bt] = MFMA(a0, hf[bt], acc[0][bt]);
          acc[1][bt] = MFMA(a1, hf[bt], acc[1][bt]);
        }
      }
    } else {
      f32x4 aL[4];
      #pragma unroll
      for (int bt = 0; bt < 4; bt++) aL[bt] = (f32x4){0.f, 0.f, 0.f, 0.f};
      const unsigned short* lpA = WlinPk + ((size_t)lt * 64 + lane) * 8;
      #pragma unroll 4
      for (int kk = 0; kk < 16; kk++) {
        short8 hf[4];
        #pragma unroll
        for (int bt = 0; bt < 4; bt++)
          hf[bt] = *(const short8*)&h_buf[cur][bt * 16 + c][kk * 32 + q * 8];
        const short8 a0 = *(const short8*)(apA + (size_t)kk * 16384);
        const short8 a1 = *(const short8*)(apA + (size_t)kk * 16384 + 512);
        const short8 aw = *(const short8*)(lpA + (size_t)kk * 2048);
        #pragma unroll
        for (int bt = 0; bt < 4; bt++) {
          acc[0][bt] = MFMA(a0, hf[bt], acc[0][bt]);
          acc[1][bt] = MFMA(a1, hf[bt], acc[1][bt]);
          aL[bt]     = MFMA(aw, hf[bt], aL[bt]);
        }
      }
      // head store: out_t = W_lin*h^s + b_lin, t = t0 + s - W_UP - 1
      if (s > W_UP) {
        const int t = t0 + s - W_UP - 1;
        #pragma unroll
        for (int bt = 0; bt < 4; bt++) {
          const f32x4 res = aL[bt] + blin4;
          float* op = out + ((size_t)(bt * 16 + c) * T_LEN + t) * N_OUT + lt * 16 + q * 4;
          *(f32x4*)op = res;
        }
      }
    }
    // ---- + W_ih x u_t: K = 64, same accumulators (all waves) ----
    {
      const unsigned short* wpA = WihPk + ((size_t)(2 * w) * 64 + lane) * 8;
      #pragma unroll
      for (int kk = 0; kk < 2; kk++) {
        short8 uf[4];
        #pragma unroll
        for (int bt = 0; bt < 4; bt++)
          uf[bt] = *(const short8*)&u_buf[cur][bt * 16 + c][kk * 32 + q * 8];
        const short8 a0 = *(const short8*)(wpA + (size_t)kk * 16384);
        const short8 a1 = *(const short8*)(wpA + (size_t)kk * 16384 + 512);
        #pragma unroll
        for (int bt = 0; bt < 4; bt++) {
          acc[0][bt] = MFMA(a0, uf[bt], acc[0][bt]);
          acc[1][bt] = MFMA(a1, uf[bt], acc[1][bt]);
        }
      }
    }

    // ---- epilogue: h_new = tanh_z(acc + bias) -> h_buf[nxt] (b64 writes) ----
    #pragma unroll
    for (int mt = 0; mt < 2; mt++) {
      #pragma unroll
      for (int bt = 0; bt < 4; bt++) {
        const unsigned lo = pack2bf(tanh_z(acc[mt][bt][0] + bsum[mt][0]),
                                    tanh_z(acc[mt][bt][1] + bsum[mt][1]));
        const unsigned hi = pack2bf(tanh_z(acc[mt][bt][2] + bsum[mt][2]),
                                    tanh_z(acc[mt][bt][3] + bsum[mt][3]));
        unsigned* d = (unsigned*)&h_buf[nxt][bt * 16 + c][(2 * w + mt) * 16 + q * 4];
        d[0] = lo; d[1] = hi;
      }
    }
    {
      const int row = tid >> 4, cb = (tid & 15) * 4;
      unsigned* d = (unsigned*)&u_buf[nxt][row][cb];
      d[0] = pack2bf(up0, up1); d[1] = pack2bf(up2, up3);
    }
    __syncthreads();   // single barrier per step
  }

  // ---- final head-only step: sigma = S_FULL consumes h^13 (buf [S_FULL&1]) ----
  if (wl) {
    const int cur = S_FULL & 1;
    f32x4 aL[4];
    #pragma unroll
    for (int bt = 0; bt < 4; bt++) aL[bt] = (f32x4){0.f, 0.f, 0.f, 0.f};
    const unsigned short* lpA = WlinPk + ((size_t)lt * 64 + lane) * 8;
    #pragma unroll 4
    for (int kk = 0; kk < 16; kk++) {
      const short8 aw = *(const short8*)(lpA + (size_t)kk * 2048);
      #pragma unroll
      for (int bt = 0; bt < 4; bt++) {
        const short8 hf = *(const short8*)&h_buf[cur][bt * 16 + c][kk * 32 + q * 8];
        aL[bt] = MFMA(aw, hf, aL[bt]);
      }
    }
    const int t = t0 + L_CH - 1;
    #pragma unroll
    for (int bt = 0; bt < 4; bt++) {
      const f32x4 res = aL[bt] + blin4;
      float* op = out + ((size_t)(bt * 16 + c) * T_LEN + t) * N_OUT + lt * 16 + q * 4;
      *(f32x4*)op = res;
    }
  }
}

extern "C" void kernel_launch(void* const* d_in, const int* in_sizes, int n_in,
                              void* d_out, int out_size, void* d_ws, size_t ws_size,
                              hipStream_t stream) {
  const float* u     = (const float*)d_in[0];
  const float* W_ih  = (const float*)d_in[1];
  const float* W_hh  = (const float*)d_in[2];
  const float* b_ih  = (const float*)d_in[3];
  const float* b_hh  = (const float*)d_in[4];
  const float* omega = (const float*)d_in[5];
  const float* W_lin = (const float*)d_in[6];
  const float* b_lin = (const float*)d_in[7];
  float* out = (float*)d_out;

  unsigned short* Apk    = (unsigned short*)d_ws;                 // 512*512 bf16
  unsigned short* WihPk  = Apk + (size_t)H_DIM * H_DIM;           // 512*64
  unsigned short* WlinPk = WihPk + (size_t)H_DIM * N_IN;          // 64*512

  pack_kernel<<<34, 256, 0, stream>>>(W_ih, W_hh, omega, W_lin, Apk, WihPk, WlinPk);
  rnn_kernel<<<T_LEN / L_CH, 1024, 0, stream>>>(u, b_ih, b_hh, b_lin,
                                                Apk, WihPk, WlinPk, out);
}